// Round 1
// baseline (655.727 us; speedup 1.0000x reference)
//
#include <hip/hip_runtime.h>
#include <cstdint>
#include <cstddef>

#define TPB 256

// ---------------------------------------------------------------------------
// Edge dtype detection: int64 edge values < 10000 -> all odd 32-bit words zero
// ---------------------------------------------------------------------------
__global__ void detect_kernel(const unsigned int* __restrict__ w, int* __restrict__ flag) {
  __shared__ int any32;
  if (threadIdx.x == 0) any32 = 0;
  __syncthreads();
  for (int i = threadIdx.x; i < 1024; i += TPB)
    if (w[2 * i + 1] != 0u) any32 = 1;
  __syncthreads();
  if (threadIdx.x == 0) *flag = any32;   // 1 -> int32 data, 0 -> int64 data
}

__global__ void decode_kernel(const void* __restrict__ raw, const int* __restrict__ flag,
                              int* __restrict__ src, int* __restrict__ dst, int E, int n) {
  int i = blockIdx.x * TPB + threadIdx.x;
  int tot = E + n;
  if (i >= tot) return;
  if (i < E) {
    if (*flag) {
      const int* p = (const int*)raw;
      src[i] = p[i];
      dst[i] = p[E + i];
    } else {
      const long long* p = (const long long*)raw;
      src[i] = (int)p[i];
      dst[i] = (int)p[E + i];
    }
  } else {                 // self loops appended
    src[i] = i - E;
    dst[i] = i - E;
  }
}

// ---------------------------------------------------------------------------
// CSR build: count -> scan -> fill
// ---------------------------------------------------------------------------
__global__ void count_kernel(const int* __restrict__ dst, int* __restrict__ counts, int etot) {
  int i = blockIdx.x * TPB + threadIdx.x;
  if (i < etot) atomicAdd(&counts[dst[i]], 1);
}

__global__ void scan_kernel(const int* __restrict__ counts, int* __restrict__ row_ptr, int n) {
  __shared__ int part[TPB];
  int tid = threadIdx.x;
  int chunk = (n + TPB - 1) / TPB;
  int begin = tid * chunk;
  int end = begin + chunk; if (end > n) end = n;
  int s = 0;
  for (int i = begin; i < end && i < n; i++) s += counts[i];
  part[tid] = s;
  __syncthreads();
  for (int off = 1; off < TPB; off <<= 1) {
    int v = (tid >= off) ? part[tid - off] : 0;
    __syncthreads();
    part[tid] += v;
    __syncthreads();
  }
  int base = (tid == 0) ? 0 : part[tid - 1];
  for (int i = begin; i < end && i < n; i++) { row_ptr[i] = base; base += counts[i]; }
  if (tid == TPB - 1) row_ptr[n] = base;
}

__global__ void fill_kernel(const int* __restrict__ src, const int* __restrict__ dst,
                            const int* __restrict__ row_ptr, int* __restrict__ fill,
                            int* __restrict__ sorted_src, int etot) {
  int i = blockIdx.x * TPB + threadIdx.x;
  if (i >= etot) return;
  int d = dst[i];
  int pos = row_ptr[d] + atomicAdd(&fill[d], 1);
  sorted_src[pos] = src[i];
}

// ---------------------------------------------------------------------------
// fp32 tiled GEMM: C[M,N] = A[M,K] @ B[K,N] (+ bias[N]).  BM=BN=64, BK=16.
// ---------------------------------------------------------------------------
__global__ __launch_bounds__(256) void gemm_kernel(
    const float* __restrict__ A, const float* __restrict__ B,
    const float* __restrict__ bias, float* __restrict__ C,
    int M, int N, int K) {
  __shared__ float As[16][65];
  __shared__ float Bs[16][66];
  int tid = threadIdx.x;
  int tx = tid & 15, ty = tid >> 4;
  int bm = blockIdx.x * 64, bn = blockIdx.y * 64;
  float acc[4][4] = {};
  for (int k0 = 0; k0 < K; k0 += 16) {
    for (int idx = tid; idx < 1024; idx += 256) {
      int r = idx >> 4, c = idx & 15;
      int gr = bm + r;
      As[c][r] = (gr < M) ? A[(size_t)gr * K + k0 + c] : 0.f;
    }
    for (int idx = tid; idx < 1024; idx += 256) {
      int r = idx >> 6, c = idx & 63;
      Bs[r][c] = B[(size_t)(k0 + r) * N + bn + c];
    }
    __syncthreads();
#pragma unroll
    for (int k = 0; k < 16; k++) {
      float a[4], b[4];
#pragma unroll
      for (int i = 0; i < 4; i++) a[i] = As[k][ty * 4 + i];
#pragma unroll
      for (int j = 0; j < 4; j++) b[j] = Bs[k][tx * 4 + j];
#pragma unroll
      for (int i = 0; i < 4; i++)
#pragma unroll
        for (int j = 0; j < 4; j++) acc[i][j] += a[i] * b[j];
    }
    __syncthreads();
  }
#pragma unroll
  for (int i = 0; i < 4; i++) {
    int gr = bm + ty * 4 + i;
    if (gr >= M) continue;
#pragma unroll
    for (int j = 0; j < 4; j++) {
      int gc = bn + tx * 4 + j;
      float v = acc[i][j];
      if (bias) v += bias[gc];
      C[(size_t)gr * N + gc] = v;
    }
  }
}

// ---------------------------------------------------------------------------
// attention coefficients: es[n,h] = dot(g[n,h,:], a_src[h,:]), same for ed
// block = C threads, one node per block
// ---------------------------------------------------------------------------
template <int H, int C>
__global__ void attn_coeff_kernel(const float* __restrict__ g,
                                  const float* __restrict__ asrc,
                                  const float* __restrict__ adst,
                                  float* __restrict__ es, float* __restrict__ ed, int n) {
  int v = blockIdx.x;
  int tid = threadIdx.x;
  __shared__ float rs[2], rd[2];
  const float* grow = g + (size_t)v * (H * C);
  for (int h = 0; h < H; ++h) {
    float gv = grow[h * C + tid];
    float p1 = gv * asrc[h * C + tid];
    float p2 = gv * adst[h * C + tid];
#pragma unroll
    for (int off = 32; off > 0; off >>= 1) {
      p1 += __shfl_down(p1, off);
      p2 += __shfl_down(p2, off);
    }
    if ((tid & 63) == 0) { rs[tid >> 6] = p1; rd[tid >> 6] = p2; }
    __syncthreads();
    if (tid == 0) {
      float s1 = rs[0], s2 = rd[0];
      if (C > 64) { s1 += rs[1]; s2 += rd[1]; }
      es[(size_t)v * H + h] = s1;
      ed[(size_t)v * H + h] = s2;
    }
    __syncthreads();
  }
}

// ---------------------------------------------------------------------------
// Per-dst-node softmax + aggregation.  One block (256 thr) per node.
// out[v,c] = (1/H) * sum_h sum_e w(e,h) * g[src_e, h, c]  + bias[c]
// ---------------------------------------------------------------------------
template <int H, int C>
__global__ __launch_bounds__(256) void gat_aggregate_kernel(
    const int* __restrict__ row_ptr, const int* __restrict__ srcs,
    const float* __restrict__ g, const float* __restrict__ es,
    const float* __restrict__ ed, const float* __restrict__ bias,
    float* __restrict__ out) {
  constexpr int T = 256;
  constexpr int NG = T / H;
  constexpr int HC = H * C;
  constexpr int ACC = (HC + T - 1) / T;
  constexpr int CHUNK = 64;

  const int v = blockIdx.x;
  const int tid = threadIdx.x;
  const int h = tid & (H - 1);
  const int grp = tid / H;

  __shared__ float red[T];
  __shared__ float mh[H];
  __shared__ float invd[H];
  __shared__ float edv[H];
  __shared__ float wlds[CHUNK * H];

  const int begin = row_ptr[v];
  const int deg = row_ptr[v + 1] - begin;

  if (tid < H) edv[tid] = ed[(size_t)v * H + tid];
  __syncthreads();

  // pass 1: per-head max
  float pm = -1e30f;
  for (int j = grp; j < deg; j += NG) {
    int s = srcs[begin + j];
    float a = es[(size_t)s * H + h] + edv[h];
    a = a > 0.f ? a : 0.2f * a;
    pm = fmaxf(pm, a);
  }
  red[tid] = pm;
  __syncthreads();
  if (tid < H) {
    float m = -1e30f;
    for (int gg = 0; gg < NG; gg++) m = fmaxf(m, red[gg * H + tid]);
    mh[tid] = m;
  }
  __syncthreads();

  // pass 2: denominator
  float ps = 0.f;
  for (int j = grp; j < deg; j += NG) {
    int s = srcs[begin + j];
    float a = es[(size_t)s * H + h] + edv[h];
    a = a > 0.f ? a : 0.2f * a;
    ps += expf(a - mh[h]);
  }
  red[tid] = ps;
  __syncthreads();
  if (tid < H) {
    float d = 0.f;
    for (int gg = 0; gg < NG; gg++) d += red[gg * H + tid];
    invd[tid] = 1.0f / (d + 1e-16f);
  }

  // pass 3: weighted aggregation, chunked through LDS weights
  float acc[ACC];
#pragma unroll
  for (int k = 0; k < ACC; k++) acc[k] = 0.f;

  for (int base = 0; base < deg; base += CHUNK) {
    int cnt = deg - base; if (cnt > CHUNK) cnt = CHUNK;
    __syncthreads();
    for (int idx = tid; idx < cnt * H; idx += T) {
      int j = idx / H, hh = idx % H;
      int s = srcs[begin + base + j];
      float a = es[(size_t)s * H + hh] + edv[hh];
      a = a > 0.f ? a : 0.2f * a;
      wlds[j * H + hh] = expf(a - mh[hh]) * invd[hh];
    }
    __syncthreads();
    for (int j = 0; j < cnt; j++) {
      int s = srcs[begin + base + j];
      const float* grow = g + (size_t)s * HC;
#pragma unroll
      for (int k = 0; k < ACC; k++) {
        int idx = tid + k * T;
        if (idx < HC) {
          int hh = idx / C;
          acc[k] += wlds[j * H + hh] * grow[idx];
        }
      }
    }
  }

  // head-mean epilogue
  float part = 0.f;
#pragma unroll
  for (int k = 0; k < ACC; k++) part += acc[k];
  __syncthreads();
  red[tid] = part;
  __syncthreads();
  if (tid < C) {
    float s = 0.f;
    for (int r = tid; r < T; r += C) s += red[r];
    out[(size_t)v * C + tid] = s * (1.0f / H) + bias[tid];
  }
}

// ---------------------------------------------------------------------------
// BN column stats: sums[c] = sum x[:,c], sums[C+c] = sum x[:,c]^2
// ---------------------------------------------------------------------------
template <int C>
__global__ void bn_stats_kernel(const float* __restrict__ x, int n, float* __restrict__ sums) {
  constexpr int T = 256;
  constexpr int RPI = T / C;
  constexpr int ITER = 64;
  constexpr int ROWS = RPI * ITER;
  int c = threadIdx.x % C;
  int r0 = threadIdx.x / C;
  int rowBase = blockIdx.x * ROWS;
  float s = 0.f, q = 0.f;
  for (int it = 0; it < ITER; ++it) {
    int r = rowBase + it * RPI + r0;
    if (r < n) {
      float v = x[(size_t)r * C + c];
      s += v; q += v * v;
    }
  }
  __shared__ float ls[T], lq[T];
  ls[threadIdx.x] = s; lq[threadIdx.x] = q;
  __syncthreads();
  if (threadIdx.x < C) {
    float ts = 0.f, tq = 0.f;
    for (int r = 0; r < RPI; ++r) { ts += ls[c + r * C]; tq += lq[c + r * C]; }
    atomicAdd(&sums[c], ts);
    atomicAdd(&sums[C + c], tq);
  }
}

// ---------------------------------------------------------------------------
// out = elu((x - mu) * rsqrt(var+eps) * gamma + beta) + res
// ---------------------------------------------------------------------------
template <int C>
__global__ void bn_elu_res_kernel(const float* __restrict__ x, const float* __restrict__ sums,
                                  const float* __restrict__ gamma, const float* __restrict__ beta,
                                  const float* __restrict__ res, float* __restrict__ out, int n) {
  int i = blockIdx.x * TPB + threadIdx.x;
  if (i >= n * C) return;
  int c = i % C;
  float inv_n = 1.0f / (float)n;
  float mu = sums[c] * inv_n;
  float var = sums[C + c] * inv_n - mu * mu;
  float y = (x[i] - mu) * rsqrtf(var + 1e-5f) * gamma[c] + beta[c];
  y = y > 0.f ? y : expm1f(y);
  out[i] = y + res[i];
}

// ---------------------------------------------------------------------------
// host launch
// ---------------------------------------------------------------------------
extern "C" void kernel_launch(void* const* d_in, const int* in_sizes, int n_in,
                              void* d_out, int out_size, void* d_ws, size_t ws_size,
                              hipStream_t stream) {
  const float* x   = (const float*)d_in[0];
  const void*  ei  = d_in[1];
  const float* Wp  = (const float*)d_in[2];
  const float* bp  = (const float*)d_in[3];
  const float* W0  = (const float*)d_in[4];
  const float* as0 = (const float*)d_in[5];
  const float* ad0 = (const float*)d_in[6];
  const float* b0  = (const float*)d_in[7];
  const float* g0  = (const float*)d_in[8];
  const float* be0 = (const float*)d_in[9];
  const float* W1  = (const float*)d_in[10];
  const float* as1 = (const float*)d_in[11];
  const float* ad1 = (const float*)d_in[12];
  const float* b1  = (const float*)d_in[13];
  const float* g1  = (const float*)d_in[14];
  const float* be1 = (const float*)d_in[15];
  const float* W2  = (const float*)d_in[16];
  const float* as2 = (const float*)d_in[17];
  const float* ad2 = (const float*)d_in[18];
  const float* b2  = (const float*)d_in[19];
  const float* g2  = (const float*)d_in[20];
  const float* be2 = (const float*)d_in[21];
  const float* Wr  = (const float*)d_in[22];
  const float* br  = (const float*)d_in[23];

  const int N = in_sizes[0] / 64;       // 10000
  const int E = in_sizes[1] / 2;        // 160000
  const int ETOT = E + N;               // with self loops

  // workspace bump allocator (256B aligned)
  char* wsp = (char*)d_ws;
  size_t off = 0;
  auto alloc = [&](size_t bytes) -> void* {
    void* p = wsp + off;
    off += (bytes + 255) & ~(size_t)255;
    return p;
  };
  int*   flag    = (int*)alloc(4);
  int*   e_src   = (int*)alloc((size_t)ETOT * 4);
  int*   e_dst   = (int*)alloc((size_t)ETOT * 4);
  int*   counts  = (int*)alloc((size_t)N * 4);
  int*   fill    = (int*)alloc((size_t)N * 4);
  int*   row_ptr = (int*)alloc((size_t)(N + 1) * 4);
  int*   s_src   = (int*)alloc((size_t)ETOT * 4);
  float* hA      = (float*)alloc((size_t)N * 128 * 4);
  float* hB      = (float*)alloc((size_t)N * 128 * 4);
  float* gbuf    = (float*)alloc((size_t)N * 1024 * 4);
  float* gat     = (float*)alloc((size_t)N * 128 * 4);
  float* es      = (float*)alloc((size_t)N * 8 * 4);
  float* ed      = (float*)alloc((size_t)N * 8 * 4);
  float* bnsum   = (float*)alloc(2 * 128 * 4);

  const int egrid = (ETOT + TPB - 1) / TPB;
  const int mgrid = (N + 63) / 64;      // 157

  // ---- graph prep ----
  detect_kernel<<<1, TPB, 0, stream>>>((const unsigned int*)ei, flag);
  decode_kernel<<<egrid, TPB, 0, stream>>>(ei, flag, e_src, e_dst, E, N);
  hipMemsetAsync(counts, 0, (size_t)N * 4, stream);
  hipMemsetAsync(fill, 0, (size_t)N * 4, stream);
  count_kernel<<<egrid, TPB, 0, stream>>>(e_dst, counts, ETOT);
  scan_kernel<<<1, TPB, 0, stream>>>(counts, row_ptr, N);
  fill_kernel<<<egrid, TPB, 0, stream>>>(e_src, e_dst, row_ptr, fill, s_src, ETOT);

  // ---- input projection: hA = x @ Wp + bp  (N x 128) ----
  gemm_kernel<<<dim3(mgrid, 2), 256, 0, stream>>>(x, Wp, bp, hA, N, 128, 64);

  // ---- layer 0 (H=8, C=128), residual = hA, out -> hB ----
  gemm_kernel<<<dim3(mgrid, 16), 256, 0, stream>>>(hA, W0, nullptr, gbuf, N, 1024, 128);
  attn_coeff_kernel<8, 128><<<N, 128, 0, stream>>>(gbuf, as0, ad0, es, ed, N);
  gat_aggregate_kernel<8, 128><<<N, 256, 0, stream>>>(row_ptr, s_src, gbuf, es, ed, b0, gat);
  hipMemsetAsync(bnsum, 0, 2 * 128 * 4, stream);
  bn_stats_kernel<128><<<(N + 127) / 128, 256, 0, stream>>>(gat, N, bnsum);
  bn_elu_res_kernel<128><<<(N * 128 + TPB - 1) / TPB, TPB, 0, stream>>>(gat, bnsum, g0, be0, hA, hB, N);

  // ---- layer 1 (H=8, C=128), residual = hB, out -> hA ----
  gemm_kernel<<<dim3(mgrid, 16), 256, 0, stream>>>(hB, W1, nullptr, gbuf, N, 1024, 128);
  attn_coeff_kernel<8, 128><<<N, 128, 0, stream>>>(gbuf, as1, ad1, es, ed, N);
  gat_aggregate_kernel<8, 128><<<N, 256, 0, stream>>>(row_ptr, s_src, gbuf, es, ed, b1, gat);
  hipMemsetAsync(bnsum, 0, 2 * 128 * 4, stream);
  bn_stats_kernel<128><<<(N + 127) / 128, 256, 0, stream>>>(gat, N, bnsum);
  bn_elu_res_kernel<128><<<(N * 128 + TPB - 1) / TPB, TPB, 0, stream>>>(gat, bnsum, g1, be1, hB, hA, N);

  // ---- layer 2 (H=1, C=64), residual = hA @ Wr + br, out -> d_out ----
  gemm_kernel<<<dim3(mgrid, 1), 256, 0, stream>>>(hA, Wr, br, hB, N, 64, 128);     // hr in hB
  gemm_kernel<<<dim3(mgrid, 1), 256, 0, stream>>>(hA, W2, nullptr, gbuf, N, 64, 128);
  attn_coeff_kernel<1, 64><<<N, 64, 0, stream>>>(gbuf, as2, ad2, es, ed, N);
  gat_aggregate_kernel<1, 64><<<N, 256, 0, stream>>>(row_ptr, s_src, gbuf, es, ed, b2, gat);
  hipMemsetAsync(bnsum, 0, 2 * 64 * 4, stream);
  bn_stats_kernel<64><<<(N + 255) / 256, 256, 0, stream>>>(gat, N, bnsum);
  bn_elu_res_kernel<64><<<(N * 64 + TPB - 1) / TPB, TPB, 0, stream>>>(gat, bnsum, g2, be2, hB, (float*)d_out, N);
}

// Round 2
// 503.412 us; speedup vs baseline: 1.3026x; 1.3026x over previous
//
#include <hip/hip_runtime.h>
#include <hip/hip_bf16.h>
#include <cstdint>
#include <cstddef>

#define TPB 256

typedef __attribute__((ext_vector_type(8))) short bf16x8;
typedef __attribute__((ext_vector_type(4))) float f32x4;

// ---------------------------------------------------------------------------
// Edge dtype detection: int64 edge values < 10000 -> all odd 32-bit words zero
// ---------------------------------------------------------------------------
__global__ void detect_kernel(const unsigned int* __restrict__ w, int* __restrict__ flag) {
  __shared__ int any32;
  if (threadIdx.x == 0) any32 = 0;
  __syncthreads();
  for (int i = threadIdx.x; i < 1024; i += TPB)
    if (w[2 * i + 1] != 0u) any32 = 1;
  __syncthreads();
  if (threadIdx.x == 0) *flag = any32;   // 1 -> int32 data, 0 -> int64 data
}

__global__ void decode_kernel(const void* __restrict__ raw, const int* __restrict__ flag,
                              int* __restrict__ src, int* __restrict__ dst, int E, int n) {
  int i = blockIdx.x * TPB + threadIdx.x;
  int tot = E + n;
  if (i >= tot) return;
  if (i < E) {
    if (*flag) {
      const int* p = (const int*)raw;
      src[i] = p[i];
      dst[i] = p[E + i];
    } else {
      const long long* p = (const long long*)raw;
      src[i] = (int)p[i];
      dst[i] = (int)p[E + i];
    }
  } else {                 // self loops appended
    src[i] = i - E;
    dst[i] = i - E;
  }
}

// ---------------------------------------------------------------------------
// CSR build: count -> scan -> fill
// ---------------------------------------------------------------------------
__global__ void count_kernel(const int* __restrict__ dst, int* __restrict__ counts, int etot) {
  int i = blockIdx.x * TPB + threadIdx.x;
  if (i < etot) atomicAdd(&counts[dst[i]], 1);
}

__global__ void scan_kernel(const int* __restrict__ counts, int* __restrict__ row_ptr, int n) {
  __shared__ int part[TPB];
  int tid = threadIdx.x;
  int chunk = (n + TPB - 1) / TPB;
  int begin = tid * chunk;
  int end = begin + chunk; if (end > n) end = n;
  int s = 0;
  for (int i = begin; i < end && i < n; i++) s += counts[i];
  part[tid] = s;
  __syncthreads();
  for (int off = 1; off < TPB; off <<= 1) {
    int v = (tid >= off) ? part[tid - off] : 0;
    __syncthreads();
    part[tid] += v;
    __syncthreads();
  }
  int base = (tid == 0) ? 0 : part[tid - 1];
  for (int i = begin; i < end && i < n; i++) { row_ptr[i] = base; base += counts[i]; }
  if (tid == TPB - 1) row_ptr[n] = base;
}

__global__ void fill_kernel(const int* __restrict__ src, const int* __restrict__ dst,
                            const int* __restrict__ row_ptr, int* __restrict__ fill,
                            int* __restrict__ sorted_src, int etot) {
  int i = blockIdx.x * TPB + threadIdx.x;
  if (i >= etot) return;
  int d = dst[i];
  int pos = row_ptr[d] + atomicAdd(&fill[d], 1);
  sorted_src[pos] = src[i];
}

// ---------------------------------------------------------------------------
// fp32 -> bf16 convert
// ---------------------------------------------------------------------------
__global__ void f32_to_bf16_kernel(const float* __restrict__ in, __hip_bfloat16* __restrict__ out, int n) {
  int i = blockIdx.x * TPB + threadIdx.x;
  if (i < n) out[i] = __float2bfloat16(in[i]);
}

// ---------------------------------------------------------------------------
// bf16 MFMA GEMM: C[M,N] = A[M,K] @ B[K,N] (+bias). Tile 64x64, 4 waves,
// BK=32, mfma_f32_16x16x32_bf16. Optional bf16 second output.
// A,B are bf16 (as short). C fp32.
// ---------------------------------------------------------------------------
__global__ __launch_bounds__(256) void gemm_bf16_kernel(
    const short* __restrict__ A, const short* __restrict__ B,
    const float* __restrict__ bias, float* __restrict__ C,
    __hip_bfloat16* __restrict__ Cb, int M, int N, int K) {
  __shared__ short As[64][40];   // row stride 80B (16B-aligned frag reads)
  __shared__ short Bs[64][40];   // transposed: Bs[col][k]

  const int tid = threadIdx.x;
  const int lane = tid & 63;
  const int w = tid >> 6;
  const int bm = blockIdx.x * 64;
  const int bn = blockIdx.y * 64;

  f32x4 acc[4];
#pragma unroll
  for (int nt = 0; nt < 4; nt++) acc[nt] = (f32x4){0.f, 0.f, 0.f, 0.f};

  const int arow = tid >> 2;          // 0..63
  const int akk = (tid & 3) << 3;     // 0,8,16,24
  const int bc = tid & 63;            // 0..63
  const int bkg = (tid >> 6) << 3;    // 0,8,16,24

  for (int k0 = 0; k0 < K; k0 += 32) {
    // stage A (64x32)
    {
      int gr = bm + arow;
      if (gr < M) {
        *(bf16x8*)&As[arow][akk] = *(const bf16x8*)&A[(size_t)gr * K + k0 + akk];
      } else {
        bf16x8 z = {0, 0, 0, 0, 0, 0, 0, 0};
        *(bf16x8*)&As[arow][akk] = z;
      }
    }
    // stage B transposed (Bs[c][k])
    {
      bf16x8 t;
#pragma unroll
      for (int j = 0; j < 8; j++)
        t[j] = B[(size_t)(k0 + bkg + j) * N + bn + bc];
      *(bf16x8*)&Bs[bc][bkg] = t;
    }
    __syncthreads();

    bf16x8 a = *(const bf16x8*)&As[w * 16 + (lane & 15)][(lane >> 4) * 8];
#pragma unroll
    for (int nt = 0; nt < 4; nt++) {
      bf16x8 b = *(const bf16x8*)&Bs[nt * 16 + (lane & 15)][(lane >> 4) * 8];
      acc[nt] = __builtin_amdgcn_mfma_f32_16x16x32_bf16(a, b, acc[nt], 0, 0, 0);
    }
    __syncthreads();
  }

#pragma unroll
  for (int nt = 0; nt < 4; nt++) {
    int gc = bn + nt * 16 + (lane & 15);
    float bv = bias ? bias[gc] : 0.f;
#pragma unroll
    for (int q = 0; q < 4; q++) {
      int gr = bm + w * 16 + (lane >> 4) * 4 + q;
      if (gr < M) {
        float val = acc[nt][q] + bv;
        C[(size_t)gr * N + gc] = val;
        if (Cb) Cb[(size_t)gr * N + gc] = __float2bfloat16(val);
      }
    }
  }
}

// ---------------------------------------------------------------------------
// attention coefficients, H=8 C=128 vectorized: block 256, one node per block
// ---------------------------------------------------------------------------
__global__ void attn_coeff8_kernel(const float* __restrict__ g,
                                   const float* __restrict__ asrc,
                                   const float* __restrict__ adst,
                                   float* __restrict__ es, float* __restrict__ ed) {
  const int v = blockIdx.x;
  const int tid = threadIdx.x;
  float4 gv = *(const float4*)&g[(size_t)v * 1024 + 4 * tid];
  float4 av = *(const float4*)&asrc[4 * tid];
  float4 dv = *(const float4*)&adst[4 * tid];
  float p1 = gv.x * av.x + gv.y * av.y + gv.z * av.z + gv.w * av.w;
  float p2 = gv.x * dv.x + gv.y * dv.y + gv.z * dv.z + gv.w * dv.w;
#pragma unroll
  for (int off = 16; off > 0; off >>= 1) {
    p1 += __shfl_down(p1, off);
    p2 += __shfl_down(p2, off);
  }
  if ((tid & 31) == 0) {
    es[(size_t)v * 8 + (tid >> 5)] = p1;
    ed[(size_t)v * 8 + (tid >> 5)] = p2;
  }
}

// generic (used for layer 2: H=1, C=64)
template <int H, int C>
__global__ void attn_coeff_kernel(const float* __restrict__ g,
                                  const float* __restrict__ asrc,
                                  const float* __restrict__ adst,
                                  float* __restrict__ es, float* __restrict__ ed) {
  int v = blockIdx.x;
  int tid = threadIdx.x;
  __shared__ float rs[2], rd[2];
  const float* grow = g + (size_t)v * (H * C);
  for (int h = 0; h < H; ++h) {
    float gv = grow[h * C + tid];
    float p1 = gv * asrc[h * C + tid];
    float p2 = gv * adst[h * C + tid];
#pragma unroll
    for (int off = 32; off > 0; off >>= 1) {
      p1 += __shfl_down(p1, off);
      p2 += __shfl_down(p2, off);
    }
    if ((tid & 63) == 0) { rs[tid >> 6] = p1; rd[tid >> 6] = p2; }
    __syncthreads();
    if (tid == 0) {
      float s1 = rs[0], s2 = rd[0];
      if (C > 64) { s1 += rs[1]; s2 += rd[1]; }
      es[(size_t)v * H + h] = s1;
      ed[(size_t)v * H + h] = s2;
    }
    __syncthreads();
  }
}

// ---------------------------------------------------------------------------
// Per-dst softmax + aggregation, H=8 C=128 vectorized (float4 per thread).
// ---------------------------------------------------------------------------
__global__ __launch_bounds__(256) void gat_aggregate8_kernel(
    const int* __restrict__ row_ptr, const int* __restrict__ srcs,
    const float* __restrict__ g, const float* __restrict__ es,
    const float* __restrict__ ed, const float* __restrict__ bias,
    float* __restrict__ out) {
  constexpr int T = 256, H = 8, HC = 1024, CHUNK = 64;
  const int v = blockIdx.x;
  const int tid = threadIdx.x;
  const int h = tid & 7;        // passes 1/2
  const int grp = tid >> 3;     // 32 edge-groups
  const int hh = tid >> 5;      // pass-3 head (4*tid/128)

  __shared__ float red[T];
  __shared__ float mh[H], invd[H], edv[H];
  __shared__ float wlds[CHUNK * H];
  __shared__ int slds[CHUNK];
  __shared__ float4 red4[T];

  const int begin = row_ptr[v];
  const int deg = row_ptr[v + 1] - begin;

  if (tid < H) edv[tid] = ed[(size_t)v * H + tid];
  __syncthreads();

  // pass 1: per-head max
  float pm = -1e30f;
  for (int j = grp; j < deg; j += 32) {
    int s = srcs[begin + j];
    float a = es[(size_t)s * H + h] + edv[h];
    a = a > 0.f ? a : 0.2f * a;
    pm = fmaxf(pm, a);
  }
  red[tid] = pm;
  __syncthreads();
  if (tid < H) {
    float m = -1e30f;
    for (int gg = 0; gg < 32; gg++) m = fmaxf(m, red[gg * H + tid]);
    mh[tid] = m;
  }
  __syncthreads();

  // pass 2: denominator
  float ps = 0.f;
  for (int j = grp; j < deg; j += 32) {
    int s = srcs[begin + j];
    float a = es[(size_t)s * H + h] + edv[h];
    a = a > 0.f ? a : 0.2f * a;
    ps += expf(a - mh[h]);
  }
  red[tid] = ps;
  __syncthreads();
  if (tid < H) {
    float d = 0.f;
    for (int gg = 0; gg < 32; gg++) d += red[gg * H + tid];
    invd[tid] = 1.0f / (d + 1e-16f);
  }

  // pass 3: weighted aggregation, float4 per thread
  float4 acc = make_float4(0.f, 0.f, 0.f, 0.f);
  for (int base = 0; base < deg; base += CHUNK) {
    int cnt = deg - base; if (cnt > CHUNK) cnt = CHUNK;
    __syncthreads();
    for (int idx = tid; idx < cnt * H; idx += T) {
      int j = idx >> 3, hx = idx & 7;
      int s = srcs[begin + base + j];
      if (hx == 0) slds[j] = s;
      float a = es[(size_t)s * H + hx] + edv[hx];
      a = a > 0.f ? a : 0.2f * a;
      wlds[idx] = expf(a - mh[hx]) * invd[hx];
    }
    __syncthreads();
    int j = 0;
    for (; j + 2 <= cnt; j += 2) {
      int s0 = slds[j], s1 = slds[j + 1];
      float w0 = wlds[j * 8 + hh], w1 = wlds[(j + 1) * 8 + hh];
      float4 g0 = *(const float4*)&g[(size_t)s0 * HC + 4 * tid];
      float4 g1 = *(const float4*)&g[(size_t)s1 * HC + 4 * tid];
      acc.x += w0 * g0.x; acc.y += w0 * g0.y; acc.z += w0 * g0.z; acc.w += w0 * g0.w;
      acc.x += w1 * g1.x; acc.y += w1 * g1.y; acc.z += w1 * g1.z; acc.w += w1 * g1.w;
    }
    if (j < cnt) {
      int s0 = slds[j];
      float w0 = wlds[j * 8 + hh];
      float4 g0 = *(const float4*)&g[(size_t)s0 * HC + 4 * tid];
      acc.x += w0 * g0.x; acc.y += w0 * g0.y; acc.z += w0 * g0.z; acc.w += w0 * g0.w;
    }
  }

  __syncthreads();
  red4[tid] = acc;
  __syncthreads();
  if (tid < 32) {
    float4 s = red4[tid];
#pragma unroll
    for (int hx = 1; hx < 8; hx++) {
      float4 t = red4[tid + 32 * hx];
      s.x += t.x; s.y += t.y; s.z += t.z; s.w += t.w;
    }
    int c0 = 4 * tid;
    out[(size_t)v * 128 + c0 + 0] = s.x * 0.125f + bias[c0 + 0];
    out[(size_t)v * 128 + c0 + 1] = s.y * 0.125f + bias[c0 + 1];
    out[(size_t)v * 128 + c0 + 2] = s.z * 0.125f + bias[c0 + 2];
    out[(size_t)v * 128 + c0 + 3] = s.w * 0.125f + bias[c0 + 3];
  }
}

// generic (used for layer 2: H=1, C=64)
template <int H, int C>
__global__ __launch_bounds__(256) void gat_aggregate_kernel(
    const int* __restrict__ row_ptr, const int* __restrict__ srcs,
    const float* __restrict__ g, const float* __restrict__ es,
    const float* __restrict__ ed, const float* __restrict__ bias,
    float* __restrict__ out) {
  constexpr int T = 256;
  constexpr int NG = T / H;
  constexpr int HC = H * C;
  constexpr int ACC = (HC + T - 1) / T;
  constexpr int CHUNK = 64;

  const int v = blockIdx.x;
  const int tid = threadIdx.x;
  const int h = tid & (H - 1);
  const int grp = tid / H;

  __shared__ float red[T];
  __shared__ float mh[H];
  __shared__ float invd[H];
  __shared__ float edv[H];
  __shared__ float wlds[CHUNK * H];

  const int begin = row_ptr[v];
  const int deg = row_ptr[v + 1] - begin;

  if (tid < H) edv[tid] = ed[(size_t)v * H + tid];
  __syncthreads();

  float pm = -1e30f;
  for (int j = grp; j < deg; j += NG) {
    int s = srcs[begin + j];
    float a = es[(size_t)s * H + h] + edv[h];
    a = a > 0.f ? a : 0.2f * a;
    pm = fmaxf(pm, a);
  }
  red[tid] = pm;
  __syncthreads();
  if (tid < H) {
    float m = -1e30f;
    for (int gg = 0; gg < NG; gg++) m = fmaxf(m, red[gg * H + tid]);
    mh[tid] = m;
  }
  __syncthreads();

  float ps = 0.f;
  for (int j = grp; j < deg; j += NG) {
    int s = srcs[begin + j];
    float a = es[(size_t)s * H + h] + edv[h];
    a = a > 0.f ? a : 0.2f * a;
    ps += expf(a - mh[h]);
  }
  red[tid] = ps;
  __syncthreads();
  if (tid < H) {
    float d = 0.f;
    for (int gg = 0; gg < NG; gg++) d += red[gg * H + tid];
    invd[tid] = 1.0f / (d + 1e-16f);
  }

  float acc[ACC];
#pragma unroll
  for (int k = 0; k < ACC; k++) acc[k] = 0.f;

  for (int base = 0; base < deg; base += CHUNK) {
    int cnt = deg - base; if (cnt > CHUNK) cnt = CHUNK;
    __syncthreads();
    for (int idx = tid; idx < cnt * H; idx += T) {
      int j = idx / H, hhx = idx % H;
      int s = srcs[begin + base + j];
      float a = es[(size_t)s * H + hhx] + edv[hhx];
      a = a > 0.f ? a : 0.2f * a;
      wlds[j * H + hhx] = expf(a - mh[hhx]) * invd[hhx];
    }
    __syncthreads();
    for (int j = 0; j < cnt; j++) {
      int s = srcs[begin + base + j];
      const float* grow = g + (size_t)s * HC;
#pragma unroll
      for (int k = 0; k < ACC; k++) {
        int idx = tid + k * T;
        if (idx < HC) {
          int hhx = idx / C;
          acc[k] += wlds[j * H + hhx] * grow[idx];
        }
      }
    }
  }

  float part = 0.f;
#pragma unroll
  for (int k = 0; k < ACC; k++) part += acc[k];
  __syncthreads();
  red[tid] = part;
  __syncthreads();
  if (tid < C) {
    float s = 0.f;
    for (int r = tid; r < T; r += C) s += red[r];
    out[(size_t)v * C + tid] = s * (1.0f / H) + bias[tid];
  }
}

// ---------------------------------------------------------------------------
// BN column stats
// ---------------------------------------------------------------------------
template <int C>
__global__ void bn_stats_kernel(const float* __restrict__ x, int n, float* __restrict__ sums) {
  constexpr int T = 256;
  constexpr int RPI = T / C;
  constexpr int ITER = 64;
  constexpr int ROWS = RPI * ITER;
  int c = threadIdx.x % C;
  int r0 = threadIdx.x / C;
  int rowBase = blockIdx.x * ROWS;
  float s = 0.f, q = 0.f;
  for (int it = 0; it < ITER; ++it) {
    int r = rowBase + it * RPI + r0;
    if (r < n) {
      float v = x[(size_t)r * C + c];
      s += v; q += v * v;
    }
  }
  __shared__ float ls[T], lq[T];
  ls[threadIdx.x] = s; lq[threadIdx.x] = q;
  __syncthreads();
  if (threadIdx.x < C) {
    float ts = 0.f, tq = 0.f;
    for (int r = 0; r < RPI; ++r) { ts += ls[c + r * C]; tq += lq[c + r * C]; }
    atomicAdd(&sums[c], ts);
    atomicAdd(&sums[C + c], tq);
  }
}

// ---------------------------------------------------------------------------
// out = elu(bn(x)) + res ; optional bf16 copy of out
// ---------------------------------------------------------------------------
template <int C>
__global__ void bn_elu_res_kernel(const float* __restrict__ x, const float* __restrict__ sums,
                                  const float* __restrict__ gamma, const float* __restrict__ beta,
                                  const float* __restrict__ res, float* __restrict__ out,
                                  __hip_bfloat16* __restrict__ outb, int n) {
  int i = blockIdx.x * TPB + threadIdx.x;
  if (i >= n * C) return;
  int c = i % C;
  float inv_n = 1.0f / (float)n;
  float mu = sums[c] * inv_n;
  float var = sums[C + c] * inv_n - mu * mu;
  float y = (x[i] - mu) * rsqrtf(var + 1e-5f) * gamma[c] + beta[c];
  y = y > 0.f ? y : expm1f(y);
  y += res[i];
  out[i] = y;
  if (outb) outb[i] = __float2bfloat16(y);
}

// ---------------------------------------------------------------------------
// host launch
// ---------------------------------------------------------------------------
extern "C" void kernel_launch(void* const* d_in, const int* in_sizes, int n_in,
                              void* d_out, int out_size, void* d_ws, size_t ws_size,
                              hipStream_t stream) {
  const float* x   = (const float*)d_in[0];
  const void*  ei  = d_in[1];
  const float* Wp  = (const float*)d_in[2];
  const float* bp  = (const float*)d_in[3];
  const float* W0  = (const float*)d_in[4];
  const float* as0 = (const float*)d_in[5];
  const float* ad0 = (const float*)d_in[6];
  const float* b0  = (const float*)d_in[7];
  const float* g0  = (const float*)d_in[8];
  const float* be0 = (const float*)d_in[9];
  const float* W1  = (const float*)d_in[10];
  const float* as1 = (const float*)d_in[11];
  const float* ad1 = (const float*)d_in[12];
  const float* b1  = (const float*)d_in[13];
  const float* g1  = (const float*)d_in[14];
  const float* be1 = (const float*)d_in[15];
  const float* W2  = (const float*)d_in[16];
  const float* as2 = (const float*)d_in[17];
  const float* ad2 = (const float*)d_in[18];
  const float* b2  = (const float*)d_in[19];
  const float* g2  = (const float*)d_in[20];
  const float* be2 = (const float*)d_in[21];
  const float* Wr  = (const float*)d_in[22];
  const float* br  = (const float*)d_in[23];

  const int N = in_sizes[0] / 64;       // 10000
  const int E = in_sizes[1] / 2;        // 160000
  const int ETOT = E + N;

  char* wsp = (char*)d_ws;
  size_t off = 0;
  auto alloc = [&](size_t bytes) -> void* {
    void* p = wsp + off;
    off += (bytes + 255) & ~(size_t)255;
    return p;
  };
  int*   flag    = (int*)alloc(4);
  int*   e_src   = (int*)alloc((size_t)ETOT * 4);
  int*   e_dst   = (int*)alloc((size_t)ETOT * 4);
  int*   counts  = (int*)alloc((size_t)N * 4);
  int*   fillc   = (int*)alloc((size_t)N * 4);
  int*   row_ptr = (int*)alloc((size_t)(N + 1) * 4);
  int*   s_src   = (int*)alloc((size_t)ETOT * 4);
  float* hA      = (float*)alloc((size_t)N * 128 * 4);
  float* hB      = (float*)alloc((size_t)N * 128 * 4);
  float* gbuf    = (float*)alloc((size_t)N * 1024 * 4);
  float* gat     = (float*)alloc((size_t)N * 128 * 4);
  float* es      = (float*)alloc((size_t)N * 8 * 4);
  float* ed      = (float*)alloc((size_t)N * 8 * 4);
  float* bnsum   = (float*)alloc(2 * 128 * 4);
  __hip_bfloat16* xb  = (__hip_bfloat16*)alloc((size_t)N * 64 * 2);
  __hip_bfloat16* hAb = (__hip_bfloat16*)alloc((size_t)N * 128 * 2);
  __hip_bfloat16* hBb = (__hip_bfloat16*)alloc((size_t)N * 128 * 2);
  __hip_bfloat16* Wpb = (__hip_bfloat16*)alloc((size_t)64 * 128 * 2);
  __hip_bfloat16* W0b = (__hip_bfloat16*)alloc((size_t)128 * 1024 * 2);
  __hip_bfloat16* W1b = (__hip_bfloat16*)alloc((size_t)128 * 1024 * 2);
  __hip_bfloat16* W2b = (__hip_bfloat16*)alloc((size_t)128 * 64 * 2);
  __hip_bfloat16* Wrb = (__hip_bfloat16*)alloc((size_t)128 * 64 * 2);

  const int egrid = (ETOT + TPB - 1) / TPB;
  const int mgrid = (N + 63) / 64;      // 157
  auto cgrid = [](int n) { return (n + TPB - 1) / TPB; };

  // ---- graph prep ----
  detect_kernel<<<1, TPB, 0, stream>>>((const unsigned int*)ei, flag);
  decode_kernel<<<egrid, TPB, 0, stream>>>(ei, flag, e_src, e_dst, E, N);
  hipMemsetAsync(counts, 0, (size_t)N * 4, stream);
  hipMemsetAsync(fillc, 0, (size_t)N * 4, stream);
  count_kernel<<<egrid, TPB, 0, stream>>>(e_dst, counts, ETOT);
  scan_kernel<<<1, TPB, 0, stream>>>(counts, row_ptr, N);
  fill_kernel<<<egrid, TPB, 0, stream>>>(e_src, e_dst, row_ptr, fillc, s_src, ETOT);

  // ---- weight / input conversions ----
  f32_to_bf16_kernel<<<cgrid(N * 64), TPB, 0, stream>>>(x, xb, N * 64);
  f32_to_bf16_kernel<<<cgrid(64 * 128), TPB, 0, stream>>>(Wp, Wpb, 64 * 128);
  f32_to_bf16_kernel<<<cgrid(128 * 1024), TPB, 0, stream>>>(W0, W0b, 128 * 1024);
  f32_to_bf16_kernel<<<cgrid(128 * 1024), TPB, 0, stream>>>(W1, W1b, 128 * 1024);
  f32_to_bf16_kernel<<<cgrid(128 * 64), TPB, 0, stream>>>(W2, W2b, 128 * 64);
  f32_to_bf16_kernel<<<cgrid(128 * 64), TPB, 0, stream>>>(Wr, Wrb, 128 * 64);

  // ---- projection: hA = x @ Wp + bp (also bf16 copy hAb) ----
  gemm_bf16_kernel<<<dim3(mgrid, 2), 256, 0, stream>>>(
      (const short*)xb, (const short*)Wpb, bp, hA, hAb, N, 128, 64);

  // ---- layer 0 ----
  gemm_bf16_kernel<<<dim3(mgrid, 16), 256, 0, stream>>>(
      (const short*)hAb, (const short*)W0b, nullptr, gbuf, nullptr, N, 1024, 128);
  attn_coeff8_kernel<<<N, 256, 0, stream>>>(gbuf, as0, ad0, es, ed);
  gat_aggregate8_kernel<<<N, 256, 0, stream>>>(row_ptr, s_src, gbuf, es, ed, b0, gat);
  hipMemsetAsync(bnsum, 0, 2 * 128 * 4, stream);
  bn_stats_kernel<128><<<(N + 127) / 128, 256, 0, stream>>>(gat, N, bnsum);
  bn_elu_res_kernel<128><<<cgrid(N * 128), TPB, 0, stream>>>(gat, bnsum, g0, be0, hA, hB, hBb, N);

  // ---- layer 1 ----
  gemm_bf16_kernel<<<dim3(mgrid, 16), 256, 0, stream>>>(
      (const short*)hBb, (const short*)W1b, nullptr, gbuf, nullptr, N, 1024, 128);
  attn_coeff8_kernel<<<N, 256, 0, stream>>>(gbuf, as1, ad1, es, ed);
  gat_aggregate8_kernel<<<N, 256, 0, stream>>>(row_ptr, s_src, gbuf, es, ed, b1, gat);
  hipMemsetAsync(bnsum, 0, 2 * 128 * 4, stream);
  bn_stats_kernel<128><<<(N + 127) / 128, 256, 0, stream>>>(gat, N, bnsum);
  bn_elu_res_kernel<128><<<cgrid(N * 128), TPB, 0, stream>>>(gat, bnsum, g1, be1, hB, hA, hAb, N);

  // ---- layer 2 ----
  gemm_bf16_kernel<<<dim3(mgrid, 1), 256, 0, stream>>>(
      (const short*)hAb, (const short*)Wrb, br, hB, nullptr, N, 64, 128);    // hr
  gemm_bf16_kernel<<<dim3(mgrid, 1), 256, 0, stream>>>(
      (const short*)hAb, (const short*)W2b, nullptr, gbuf, nullptr, N, 64, 128);
  attn_coeff_kernel<1, 64><<<N, 64, 0, stream>>>(gbuf, as2, ad2, es, ed);
  gat_aggregate_kernel<1, 64><<<N, 256, 0, stream>>>(row_ptr, s_src, gbuf, es, ed, b2, gat);
  hipMemsetAsync(bnsum, 0, 2 * 64 * 4, stream);
  bn_stats_kernel<64><<<(N + 255) / 256, 256, 0, stream>>>(gat, N, bnsum);
  bn_elu_res_kernel<64><<<cgrid(N * 64), TPB, 0, stream>>>(gat, bnsum, g2, be2, hB, (float*)d_out, nullptr, N);
}

// Round 3
// 334.401 us; speedup vs baseline: 1.9609x; 1.5054x over previous
//
#include <hip/hip_runtime.h>
#include <hip/hip_bf16.h>
#include <cstdint>
#include <cstddef>

#define TPB 256

typedef __attribute__((ext_vector_type(8))) short bf16x8;
typedef __attribute__((ext_vector_type(4))) float f32x4;

static __device__ __forceinline__ float bf2f(unsigned short u) {
  union { unsigned int i; float f; } c;
  c.i = ((unsigned int)u) << 16;
  return c.f;
}

// ---------------------------------------------------------------------------
// Edge dtype detection: int64 edge values < 10000 -> all odd 32-bit words zero
// ---------------------------------------------------------------------------
__global__ void detect_kernel(const unsigned int* __restrict__ w, int* __restrict__ flag) {
  __shared__ int any32;
  if (threadIdx.x == 0) any32 = 0;
  __syncthreads();
  for (int i = threadIdx.x; i < 1024; i += TPB)
    if (w[2 * i + 1] != 0u) any32 = 1;
  __syncthreads();
  if (threadIdx.x == 0) *flag = any32;   // 1 -> int32 data, 0 -> int64 data
}

__global__ void decode_kernel(const void* __restrict__ raw, const int* __restrict__ flag,
                              int* __restrict__ src, int* __restrict__ dst, int E, int n) {
  int i = blockIdx.x * TPB + threadIdx.x;
  int tot = E + n;
  if (i >= tot) return;
  if (i < E) {
    if (*flag) {
      const int* p = (const int*)raw;
      src[i] = p[i];
      dst[i] = p[E + i];
    } else {
      const long long* p = (const long long*)raw;
      src[i] = (int)p[i];
      dst[i] = (int)p[E + i];
    }
  } else {                 // self loops appended
    src[i] = i - E;
    dst[i] = i - E;
  }
}

// ---------------------------------------------------------------------------
// CSR build: count -> scan -> fill
// ---------------------------------------------------------------------------
__global__ void count_kernel(const int* __restrict__ dst, int* __restrict__ counts, int etot) {
  int i = blockIdx.x * TPB + threadIdx.x;
  if (i < etot) atomicAdd(&counts[dst[i]], 1);
}

__global__ void scan_kernel(const int* __restrict__ counts, int* __restrict__ row_ptr, int n) {
  __shared__ int part[TPB];
  int tid = threadIdx.x;
  int chunk = (n + TPB - 1) / TPB;
  int begin = tid * chunk;
  int end = begin + chunk; if (end > n) end = n;
  int s = 0;
  for (int i = begin; i < end && i < n; i++) s += counts[i];
  part[tid] = s;
  __syncthreads();
  for (int off = 1; off < TPB; off <<= 1) {
    int v = (tid >= off) ? part[tid - off] : 0;
    __syncthreads();
    part[tid] += v;
    __syncthreads();
  }
  int base = (tid == 0) ? 0 : part[tid - 1];
  for (int i = begin; i < end && i < n; i++) { row_ptr[i] = base; base += counts[i]; }
  if (tid == TPB - 1) row_ptr[n] = base;
}

__global__ void fill_kernel(const int* __restrict__ src, const int* __restrict__ dst,
                            const int* __restrict__ row_ptr, int* __restrict__ fill,
                            int* __restrict__ sorted_src, int etot) {
  int i = blockIdx.x * TPB + threadIdx.x;
  if (i >= etot) return;
  int d = dst[i];
  int pos = row_ptr[d] + atomicAdd(&fill[d], 1);
  sorted_src[pos] = src[i];
}

// ---------------------------------------------------------------------------
// fp32 -> bf16 convert
// ---------------------------------------------------------------------------
__global__ void f32_to_bf16_kernel(const float* __restrict__ in, __hip_bfloat16* __restrict__ out, int n) {
  int i = blockIdx.x * TPB + threadIdx.x;
  if (i < n) out[i] = __float2bfloat16(in[i]);
}

// ---------------------------------------------------------------------------
// bf16 MFMA GEMM: C[M,N] = A[M,K] @ B[K,N] (+bias). Tile 64x64, 4 waves,
// BK=32, mfma_f32_16x16x32_bf16. C (f32) and Cb (bf16) both optional.
// ---------------------------------------------------------------------------
__global__ __launch_bounds__(256) void gemm_bf16_kernel(
    const short* __restrict__ A, const short* __restrict__ B,
    const float* __restrict__ bias, float* __restrict__ C,
    __hip_bfloat16* __restrict__ Cb, int M, int N, int K) {
  __shared__ short As[64][40];   // row stride 80B (16B-aligned frag reads)
  __shared__ short Bs[64][40];   // transposed: Bs[col][k]

  const int tid = threadIdx.x;
  const int lane = tid & 63;
  const int w = tid >> 6;
  const int bm = blockIdx.x * 64;
  const int bn = blockIdx.y * 64;

  f32x4 acc[4];
#pragma unroll
  for (int nt = 0; nt < 4; nt++) acc[nt] = (f32x4){0.f, 0.f, 0.f, 0.f};

  const int arow = tid >> 2;          // 0..63
  const int akk = (tid & 3) << 3;     // 0,8,16,24
  const int bc = tid & 63;            // 0..63
  const int bkg = (tid >> 6) << 3;    // 0,8,16,24

  for (int k0 = 0; k0 < K; k0 += 32) {
    // stage A (64x32)
    {
      int gr = bm + arow;
      if (gr < M) {
        *(bf16x8*)&As[arow][akk] = *(const bf16x8*)&A[(size_t)gr * K + k0 + akk];
      } else {
        bf16x8 z = {0, 0, 0, 0, 0, 0, 0, 0};
        *(bf16x8*)&As[arow][akk] = z;
      }
    }
    // stage B transposed (Bs[c][k])
    {
      bf16x8 t;
#pragma unroll
      for (int j = 0; j < 8; j++)
        t[j] = B[(size_t)(k0 + bkg + j) * N + bn + bc];
      *(bf16x8*)&Bs[bc][bkg] = t;
    }
    __syncthreads();

    bf16x8 a = *(const bf16x8*)&As[w * 16 + (lane & 15)][(lane >> 4) * 8];
#pragma unroll
    for (int nt = 0; nt < 4; nt++) {
      bf16x8 b = *(const bf16x8*)&Bs[nt * 16 + (lane & 15)][(lane >> 4) * 8];
      acc[nt] = __builtin_amdgcn_mfma_f32_16x16x32_bf16(a, b, acc[nt], 0, 0, 0);
    }
    __syncthreads();
  }

#pragma unroll
  for (int nt = 0; nt < 4; nt++) {
    int gc = bn + nt * 16 + (lane & 15);
    float bv = bias ? bias[gc] : 0.f;
#pragma unroll
    for (int q = 0; q < 4; q++) {
      int gr = bm + w * 16 + (lane >> 4) * 4 + q;
      if (gr < M) {
        float val = acc[nt][q] + bv;
        if (C) C[(size_t)gr * N + gc] = val;
        if (Cb) Cb[(size_t)gr * N + gc] = __float2bfloat16(val);
      }
    }
  }
}

// ---------------------------------------------------------------------------
// attention coefficients, H=8 C=128, bf16 input g: block 256, one node/block
// ---------------------------------------------------------------------------
__global__ void attn_coeff8_kernel(const unsigned short* __restrict__ gb,
                                   const float* __restrict__ asrc,
                                   const float* __restrict__ adst,
                                   float* __restrict__ es, float* __restrict__ ed) {
  const int v = blockIdx.x;
  const int tid = threadIdx.x;
  ushort4 gu = *(const ushort4*)&gb[(size_t)v * 1024 + 4 * tid];
  float4 av = *(const float4*)&asrc[4 * tid];
  float4 dv = *(const float4*)&adst[4 * tid];
  float gx = bf2f(gu.x), gy = bf2f(gu.y), gz = bf2f(gu.z), gw = bf2f(gu.w);
  float p1 = gx * av.x + gy * av.y + gz * av.z + gw * av.w;
  float p2 = gx * dv.x + gy * dv.y + gz * dv.z + gw * dv.w;
#pragma unroll
  for (int off = 16; off > 0; off >>= 1) {
    p1 += __shfl_down(p1, off);
    p2 += __shfl_down(p2, off);
  }
  if ((tid & 31) == 0) {
    es[(size_t)v * 8 + (tid >> 5)] = p1;
    ed[(size_t)v * 8 + (tid >> 5)] = p2;
  }
}

// f32 variant for layer 2 (H=1, C=64): one wave per node via 64-thr block
template <int H, int C>
__global__ void attn_coeff_kernel(const float* __restrict__ g,
                                  const float* __restrict__ asrc,
                                  const float* __restrict__ adst,
                                  float* __restrict__ es, float* __restrict__ ed) {
  int v = blockIdx.x;
  int tid = threadIdx.x;
  __shared__ float rs[2], rd[2];
  const float* grow = g + (size_t)v * (H * C);
  for (int h = 0; h < H; ++h) {
    float gv = grow[h * C + tid];
    float p1 = gv * asrc[h * C + tid];
    float p2 = gv * adst[h * C + tid];
#pragma unroll
    for (int off = 32; off > 0; off >>= 1) {
      p1 += __shfl_down(p1, off);
      p2 += __shfl_down(p2, off);
    }
    if ((tid & 63) == 0) { rs[tid >> 6] = p1; rd[tid >> 6] = p2; }
    __syncthreads();
    if (tid == 0) {
      float s1 = rs[0], s2 = rd[0];
      if (C > 64) { s1 += rs[1]; s2 += rd[1]; }
      es[(size_t)v * H + h] = s1;
      ed[(size_t)v * H + h] = s2;
    }
    __syncthreads();
  }
}

// ---------------------------------------------------------------------------
// Per-dst softmax + aggregation, H=8 C=128, bf16 g (ushort4 per thread).
// ---------------------------------------------------------------------------
__global__ __launch_bounds__(256) void gat_aggregate8_kernel(
    const int* __restrict__ row_ptr, const int* __restrict__ srcs,
    const unsigned short* __restrict__ gb, const float* __restrict__ es,
    const float* __restrict__ ed, const float* __restrict__ bias,
    float* __restrict__ out) {
  constexpr int T = 256, H = 8, HC = 1024, CHUNK = 64;
  const int v = blockIdx.x;
  const int tid = threadIdx.x;
  const int h = tid & 7;        // passes 1/2
  const int grp = tid >> 3;     // 32 edge-groups
  const int hh = tid >> 5;      // pass-3 head (4*tid/128)

  __shared__ float red[T];
  __shared__ float mh[H], invd[H], edv[H];
  __shared__ float wlds[CHUNK * H];
  __shared__ int slds[CHUNK];
  __shared__ float4 red4[T];

  const int begin = row_ptr[v];
  const int deg = row_ptr[v + 1] - begin;

  if (tid < H) edv[tid] = ed[(size_t)v * H + tid];
  __syncthreads();

  // pass 1: per-head max
  float pm = -1e30f;
  for (int j = grp; j < deg; j += 32) {
    int s = srcs[begin + j];
    float a = es[(size_t)s * H + h] + edv[h];
    a = a > 0.f ? a : 0.2f * a;
    pm = fmaxf(pm, a);
  }
  red[tid] = pm;
  __syncthreads();
  if (tid < H) {
    float m = -1e30f;
    for (int gg = 0; gg < 32; gg++) m = fmaxf(m, red[gg * H + tid]);
    mh[tid] = m;
  }
  __syncthreads();

  // pass 2: denominator
  float ps = 0.f;
  for (int j = grp; j < deg; j += 32) {
    int s = srcs[begin + j];
    float a = es[(size_t)s * H + h] + edv[h];
    a = a > 0.f ? a : 0.2f * a;
    ps += expf(a - mh[h]);
  }
  red[tid] = ps;
  __syncthreads();
  if (tid < H) {
    float d = 0.f;
    for (int gg = 0; gg < 32; gg++) d += red[gg * H + tid];
    invd[tid] = 1.0f / (d + 1e-16f);
  }

  // pass 3: weighted aggregation, ushort4 (4 bf16 channels) per thread
  float4 acc = make_float4(0.f, 0.f, 0.f, 0.f);
  for (int base = 0; base < deg; base += CHUNK) {
    int cnt = deg - base; if (cnt > CHUNK) cnt = CHUNK;
    __syncthreads();
    for (int idx = tid; idx < cnt * H; idx += T) {
      int j = idx >> 3, hx = idx & 7;
      int s = srcs[begin + base + j];
      if (hx == 0) slds[j] = s;
      float a = es[(size_t)s * H + hx] + edv[hx];
      a = a > 0.f ? a : 0.2f * a;
      wlds[idx] = expf(a - mh[hx]) * invd[hx];
    }
    __syncthreads();
    int j = 0;
    for (; j + 2 <= cnt; j += 2) {
      int s0 = slds[j], s1 = slds[j + 1];
      float w0 = wlds[j * 8 + hh], w1 = wlds[(j + 1) * 8 + hh];
      ushort4 u0 = *(const ushort4*)&gb[(size_t)s0 * HC + 4 * tid];
      ushort4 u1 = *(const ushort4*)&gb[(size_t)s1 * HC + 4 * tid];
      acc.x += w0 * bf2f(u0.x); acc.y += w0 * bf2f(u0.y);
      acc.z += w0 * bf2f(u0.z); acc.w += w0 * bf2f(u0.w);
      acc.x += w1 * bf2f(u1.x); acc.y += w1 * bf2f(u1.y);
      acc.z += w1 * bf2f(u1.z); acc.w += w1 * bf2f(u1.w);
    }
    if (j < cnt) {
      int s0 = slds[j];
      float w0 = wlds[j * 8 + hh];
      ushort4 u0 = *(const ushort4*)&gb[(size_t)s0 * HC + 4 * tid];
      acc.x += w0 * bf2f(u0.x); acc.y += w0 * bf2f(u0.y);
      acc.z += w0 * bf2f(u0.z); acc.w += w0 * bf2f(u0.w);
    }
  }

  __syncthreads();
  red4[tid] = acc;
  __syncthreads();
  if (tid < 32) {
    float4 s = red4[tid];
#pragma unroll
    for (int hx = 1; hx < 8; hx++) {
      float4 t = red4[tid + 32 * hx];
      s.x += t.x; s.y += t.y; s.z += t.z; s.w += t.w;
    }
    int c0 = 4 * tid;
    out[(size_t)v * 128 + c0 + 0] = s.x * 0.125f + bias[c0 + 0];
    out[(size_t)v * 128 + c0 + 1] = s.y * 0.125f + bias[c0 + 1];
    out[(size_t)v * 128 + c0 + 2] = s.z * 0.125f + bias[c0 + 2];
    out[(size_t)v * 128 + c0 + 3] = s.w * 0.125f + bias[c0 + 3];
  }
}

// ---------------------------------------------------------------------------
// Layer-2 aggregation (H=1, C=64): one WAVE per dst node, 4 nodes/block.
// All reductions via shuffles; weight/src broadcast via __shfl. No barriers.
// ---------------------------------------------------------------------------
__global__ __launch_bounds__(256) void gat_aggregate1_kernel(
    const int* __restrict__ row_ptr, const int* __restrict__ srcs,
    const float* __restrict__ g, const float* __restrict__ es,
    const float* __restrict__ ed, const float* __restrict__ bias,
    float* __restrict__ out, int n) {
  const int wave = threadIdx.x >> 6;
  const int lane = threadIdx.x & 63;
  const int v = blockIdx.x * 4 + wave;
  if (v >= n) return;

  const int begin = row_ptr[v];
  const int deg = row_ptr[v + 1] - begin;
  const float edv = ed[v];

  // pass 1: max over edges
  float pm = -1e30f;
  for (int j = lane; j < deg; j += 64) {
    float a = es[srcs[begin + j]] + edv;
    a = a > 0.f ? a : 0.2f * a;
    pm = fmaxf(pm, a);
  }
#pragma unroll
  for (int off = 32; off > 0; off >>= 1) pm = fmaxf(pm, __shfl_xor(pm, off));

  // pass 2: denominator
  float ps = 0.f;
  for (int j = lane; j < deg; j += 64) {
    float a = es[srcs[begin + j]] + edv;
    a = a > 0.f ? a : 0.2f * a;
    ps += expf(a - pm);
  }
#pragma unroll
  for (int off = 32; off > 0; off >>= 1) ps += __shfl_xor(ps, off);
  const float invd = 1.0f / (ps + 1e-16f);

  // pass 3: aggregation; lane = channel
  float acc = 0.f;
  for (int base = 0; base < deg; base += 64) {
    int cnt = deg - base; if (cnt > 64) cnt = 64;
    int sv = 0; float wv = 0.f;
    if (lane < cnt) {
      sv = srcs[begin + base + lane];
      float a = es[sv] + edv;
      a = a > 0.f ? a : 0.2f * a;
      wv = expf(a - pm) * invd;
    }
    for (int j = 0; j < cnt; j++) {
      int s = __shfl(sv, j);
      float wgt = __shfl(wv, j);
      acc += wgt * g[(size_t)s * 64 + lane];
    }
  }
  out[(size_t)v * 64 + lane] = acc + bias[lane];
}

// ---------------------------------------------------------------------------
// BN column stats
// ---------------------------------------------------------------------------
template <int C>
__global__ void bn_stats_kernel(const float* __restrict__ x, int n, float* __restrict__ sums) {
  constexpr int T = 256;
  constexpr int RPI = T / C;
  constexpr int ITER = 64;
  constexpr int ROWS = RPI * ITER;
  int c = threadIdx.x % C;
  int r0 = threadIdx.x / C;
  int rowBase = blockIdx.x * ROWS;
  float s = 0.f, q = 0.f;
  for (int it = 0; it < ITER; ++it) {
    int r = rowBase + it * RPI + r0;
    if (r < n) {
      float v = x[(size_t)r * C + c];
      s += v; q += v * v;
    }
  }
  __shared__ float ls[T], lq[T];
  ls[threadIdx.x] = s; lq[threadIdx.x] = q;
  __syncthreads();
  if (threadIdx.x < C) {
    float ts = 0.f, tq = 0.f;
    for (int r = 0; r < RPI; ++r) { ts += ls[c + r * C]; tq += lq[c + r * C]; }
    atomicAdd(&sums[c], ts);
    atomicAdd(&sums[C + c], tq);
  }
}

// ---------------------------------------------------------------------------
// out = elu(bn(x)) + res ; optional bf16 copy of out
// ---------------------------------------------------------------------------
template <int C>
__global__ void bn_elu_res_kernel(const float* __restrict__ x, const float* __restrict__ sums,
                                  const float* __restrict__ gamma, const float* __restrict__ beta,
                                  const float* __restrict__ res, float* __restrict__ out,
                                  __hip_bfloat16* __restrict__ outb, int n) {
  int i = blockIdx.x * TPB + threadIdx.x;
  if (i >= n * C) return;
  int c = i % C;
  float inv_n = 1.0f / (float)n;
  float mu = sums[c] * inv_n;
  float var = sums[C + c] * inv_n - mu * mu;
  float y = (x[i] - mu) * rsqrtf(var + 1e-5f) * gamma[c] + beta[c];
  y = y > 0.f ? y : expm1f(y);
  y += res[i];
  out[i] = y;
  if (outb) outb[i] = __float2bfloat16(y);
}

// ---------------------------------------------------------------------------
// host launch
// ---------------------------------------------------------------------------
extern "C" void kernel_launch(void* const* d_in, const int* in_sizes, int n_in,
                              void* d_out, int out_size, void* d_ws, size_t ws_size,
                              hipStream_t stream) {
  const float* x   = (const float*)d_in[0];
  const void*  ei  = d_in[1];
  const float* Wp  = (const float*)d_in[2];
  const float* bp  = (const float*)d_in[3];
  const float* W0  = (const float*)d_in[4];
  const float* as0 = (const float*)d_in[5];
  const float* ad0 = (const float*)d_in[6];
  const float* b0  = (const float*)d_in[7];
  const float* g0  = (const float*)d_in[8];
  const float* be0 = (const float*)d_in[9];
  const float* W1  = (const float*)d_in[10];
  const float* as1 = (const float*)d_in[11];
  const float* ad1 = (const float*)d_in[12];
  const float* b1  = (const float*)d_in[13];
  const float* g1  = (const float*)d_in[14];
  const float* be1 = (const float*)d_in[15];
  const float* W2  = (const float*)d_in[16];
  const float* as2 = (const float*)d_in[17];
  const float* ad2 = (const float*)d_in[18];
  const float* b2  = (const float*)d_in[19];
  const float* g2  = (const float*)d_in[20];
  const float* be2 = (const float*)d_in[21];
  const float* Wr  = (const float*)d_in[22];
  const float* br  = (const float*)d_in[23];

  const int N = in_sizes[0] / 64;       // 10000
  const int E = in_sizes[1] / 2;        // 160000
  const int ETOT = E + N;

  char* wsp = (char*)d_ws;
  size_t off = 0;
  auto alloc = [&](size_t bytes) -> void* {
    void* p = wsp + off;
    off += (bytes + 255) & ~(size_t)255;
    return p;
  };
  int*   flag    = (int*)alloc(4);
  int*   e_src   = (int*)alloc((size_t)ETOT * 4);
  int*   e_dst   = (int*)alloc((size_t)ETOT * 4);
  int*   counts  = (int*)alloc((size_t)N * 4);
  int*   fillc   = (int*)alloc((size_t)N * 4);
  int*   row_ptr = (int*)alloc((size_t)(N + 1) * 4);
  int*   s_src   = (int*)alloc((size_t)ETOT * 4);
  float* hA      = (float*)alloc((size_t)N * 128 * 4);
  float* hB      = (float*)alloc((size_t)N * 128 * 4);
  float* gbuf    = (float*)alloc((size_t)N * 64 * 4);       // layer-2 g (f32)
  float* gat     = (float*)alloc((size_t)N * 128 * 4);
  float* es      = (float*)alloc((size_t)N * 8 * 4);
  float* ed      = (float*)alloc((size_t)N * 8 * 4);
  float* bnsum   = (float*)alloc(2 * 128 * 4);
  __hip_bfloat16* gbufb = (__hip_bfloat16*)alloc((size_t)N * 1024 * 2);  // big-layer g (bf16)
  __hip_bfloat16* xb  = (__hip_bfloat16*)alloc((size_t)N * 64 * 2);
  __hip_bfloat16* hAb = (__hip_bfloat16*)alloc((size_t)N * 128 * 2);
  __hip_bfloat16* hBb = (__hip_bfloat16*)alloc((size_t)N * 128 * 2);
  __hip_bfloat16* Wpb = (__hip_bfloat16*)alloc((size_t)64 * 128 * 2);
  __hip_bfloat16* W0b = (__hip_bfloat16*)alloc((size_t)128 * 1024 * 2);
  __hip_bfloat16* W1b = (__hip_bfloat16*)alloc((size_t)128 * 1024 * 2);
  __hip_bfloat16* W2b = (__hip_bfloat16*)alloc((size_t)128 * 64 * 2);
  __hip_bfloat16* Wrb = (__hip_bfloat16*)alloc((size_t)128 * 64 * 2);

  const int egrid = (ETOT + TPB - 1) / TPB;
  const int mgrid = (N + 63) / 64;      // 157
  auto cgrid = [](int n) { return (n + TPB - 1) / TPB; };

  // ---- graph prep ----
  detect_kernel<<<1, TPB, 0, stream>>>((const unsigned int*)ei, flag);
  decode_kernel<<<egrid, TPB, 0, stream>>>(ei, flag, e_src, e_dst, E, N);
  hipMemsetAsync(counts, 0, (size_t)N * 4, stream);
  hipMemsetAsync(fillc, 0, (size_t)N * 4, stream);
  count_kernel<<<egrid, TPB, 0, stream>>>(e_dst, counts, ETOT);
  scan_kernel<<<1, TPB, 0, stream>>>(counts, row_ptr, N);
  fill_kernel<<<egrid, TPB, 0, stream>>>(e_src, e_dst, row_ptr, fillc, s_src, ETOT);

  // ---- weight / input conversions ----
  f32_to_bf16_kernel<<<cgrid(N * 64), TPB, 0, stream>>>(x, xb, N * 64);
  f32_to_bf16_kernel<<<cgrid(64 * 128), TPB, 0, stream>>>(Wp, Wpb, 64 * 128);
  f32_to_bf16_kernel<<<cgrid(128 * 1024), TPB, 0, stream>>>(W0, W0b, 128 * 1024);
  f32_to_bf16_kernel<<<cgrid(128 * 1024), TPB, 0, stream>>>(W1, W1b, 128 * 1024);
  f32_to_bf16_kernel<<<cgrid(128 * 64), TPB, 0, stream>>>(W2, W2b, 128 * 64);
  f32_to_bf16_kernel<<<cgrid(128 * 64), TPB, 0, stream>>>(Wr, Wrb, 128 * 64);

  // ---- projection: hA = x @ Wp + bp (also bf16 copy hAb) ----
  gemm_bf16_kernel<<<dim3(mgrid, 2), 256, 0, stream>>>(
      (const short*)xb, (const short*)Wpb, bp, hA, hAb, N, 128, 64);

  // ---- layer 0 (g written bf16-only) ----
  gemm_bf16_kernel<<<dim3(mgrid, 16), 256, 0, stream>>>(
      (const short*)hAb, (const short*)W0b, nullptr, nullptr, gbufb, N, 1024, 128);
  attn_coeff8_kernel<<<N, 256, 0, stream>>>((const unsigned short*)gbufb, as0, ad0, es, ed);
  gat_aggregate8_kernel<<<N, 256, 0, stream>>>(row_ptr, s_src, (const unsigned short*)gbufb, es, ed, b0, gat);
  hipMemsetAsync(bnsum, 0, 2 * 128 * 4, stream);
  bn_stats_kernel<128><<<(N + 127) / 128, 256, 0, stream>>>(gat, N, bnsum);
  bn_elu_res_kernel<128><<<cgrid(N * 128), TPB, 0, stream>>>(gat, bnsum, g0, be0, hA, hB, hBb, N);

  // ---- layer 1 ----
  gemm_bf16_kernel<<<dim3(mgrid, 16), 256, 0, stream>>>(
      (const short*)hBb, (const short*)W1b, nullptr, nullptr, gbufb, N, 1024, 128);
  attn_coeff8_kernel<<<N, 256, 0, stream>>>((const unsigned short*)gbufb, as1, ad1, es, ed);
  gat_aggregate8_kernel<<<N, 256, 0, stream>>>(row_ptr, s_src, (const unsigned short*)gbufb, es, ed, b1, gat);
  hipMemsetAsync(bnsum, 0, 2 * 128 * 4, stream);
  bn_stats_kernel<128><<<(N + 127) / 128, 256, 0, stream>>>(gat, N, bnsum);
  bn_elu_res_kernel<128><<<cgrid(N * 128), TPB, 0, stream>>>(gat, bnsum, g1, be1, hB, hA, hAb, N);

  // ---- layer 2 (H=1, C=64) ----
  gemm_bf16_kernel<<<dim3(mgrid, 1), 256, 0, stream>>>(
      (const short*)hAb, (const short*)Wrb, br, hB, nullptr, N, 64, 128);    // hr
  gemm_bf16_kernel<<<dim3(mgrid, 1), 256, 0, stream>>>(
      (const short*)hAb, (const short*)W2b, nullptr, gbuf, nullptr, N, 64, 128);
  attn_coeff_kernel<1, 64><<<N, 64, 0, stream>>>(gbuf, as2, ad2, es, ed);
  gat_aggregate1_kernel<<<(N + 3) / 4, 256, 0, stream>>>(row_ptr, s_src, gbuf, es, ed, b2, gat, N);
  hipMemsetAsync(bnsum, 0, 2 * 64 * 4, stream);
  bn_stats_kernel<64><<<(N + 255) / 256, 256, 0, stream>>>(gat, N, bnsum);
  bn_elu_res_kernel<64><<<cgrid(N * 64), TPB, 0, stream>>>(gat, bnsum, g2, be2, hB, (float*)d_out, nullptr, N);
}